// Round 1
// baseline (3568.115 us; speedup 1.0000x reference)
//
#include <hip/hip_runtime.h>
#include <hip/hip_bf16.h>

#define NN_NODES 20000
#define NE_EDGES 500000
#define KTOT 48

// ---------------------------------------------------------------------------
// Edge prep: basis[ E*8 ] float, kidx[ E*8 ] u8
// ---------------------------------------------------------------------------
__global__ void edge_prep_kernel(const float* __restrict__ pseudo,
                                 float* __restrict__ basis,
                                 unsigned char* __restrict__ kidx) {
    int e = blockIdx.x * 256 + threadIdx.x;
    if (e >= NE_EDGES) return;
    const int ks0 = 3, ks1 = 8, ks2 = 2;
    float frac[3];
    int lo[3];
    const int ksa[3] = {ks0, ks1, ks2};
#pragma unroll
    for (int d = 0; d < 3; ++d) {
        float u = pseudo[e * 3 + d] * (1.0f / 4.5f);
        u = fminf(fmaxf(u, 0.0f), 1.0f);
        float pos = u * (float)(ksa[d] - 1);
        float fl = floorf(pos);
        lo[d] = (int)fl;
        frac[d] = pos - fl;
    }
#pragma unroll
    for (int s = 0; s < 8; ++s) {
        float w = 1.0f;
        int idx[3];
#pragma unroll
        for (int d = 0; d < 3; ++d) {
            int bit = (s >> d) & 1;
            int id = lo[d] + bit;
            id = max(0, min(id, ksa[d] - 1));
            idx[d] = id;
            w *= bit ? frac[d] : (1.0f - frac[d]);
        }
        basis[e * 8 + s] = w;
        kidx[e * 8 + s] = (unsigned char)(idx[0] * 16 + idx[1] * 2 + idx[2]);
    }
}

// ---------------------------------------------------------------------------
// Zero helper (avoid hipMemsetAsync dependence)
// ---------------------------------------------------------------------------
__global__ void zero_kernel(int* __restrict__ p, int n) {
    int i = blockIdx.x * 256 + threadIdx.x;
    if (i < n) p[i] = 0;
}

// ---------------------------------------------------------------------------
// CSR build: count, scan (single block), fill
// ---------------------------------------------------------------------------
__global__ void count_kernel(const int* __restrict__ ei, int* __restrict__ counts) {
    int e = blockIdx.x * 256 + threadIdx.x;
    if (e < NE_EDGES) atomicAdd(&counts[ei[NE_EDGES + e]], 1);
}

__global__ void scan_kernel(const int* __restrict__ counts, int* __restrict__ row_start) {
    __shared__ int part[256];
    const int CH = (NN_NODES + 255) / 256;  // 79
    int t = threadIdx.x;
    int begin = t * CH;
    int end = begin + CH;
    if (end > NN_NODES) end = NN_NODES;
    int sum = 0;
    for (int i = begin; i < end && i < NN_NODES; ++i) sum += counts[i];
    part[t] = sum;
    __syncthreads();
    for (int off = 1; off < 256; off <<= 1) {
        int v = (t >= off) ? part[t - off] : 0;
        __syncthreads();
        part[t] += v;
        __syncthreads();
    }
    int run = (t == 0) ? 0 : part[t - 1];
    for (int i = begin; i < end && i < NN_NODES; ++i) {
        row_start[i] = run;
        run += counts[i];
    }
    if (t == 255) row_start[NN_NODES] = part[255];
}

__global__ void fill_kernel(const int* __restrict__ ei, const int* __restrict__ row_start,
                            int* __restrict__ cursor, int* __restrict__ edge_list) {
    int e = blockIdx.x * 256 + threadIdx.x;
    if (e < NE_EDGES) {
        int d = ei[NE_EDGES + e];
        int p = atomicAdd(&cursor[d], 1);
        edge_list[row_start[d] + p] = e;
    }
}

// ---------------------------------------------------------------------------
// Layer 1: c_in = 1. Global atomic scatter into acc1[N*48], then dense.
// ---------------------------------------------------------------------------
__global__ void scatter1_kernel(const int* __restrict__ ei, const float* __restrict__ x,
                                const float* __restrict__ basis,
                                const unsigned char* __restrict__ kidx,
                                float* __restrict__ acc1) {
    int t = blockIdx.x * 256 + threadIdx.x;
    if (t >= NE_EDGES * 8) return;
    int e = t >> 3;
    int src = ei[e];
    int dst = ei[NE_EDGES + e];
    atomicAdd(&acc1[dst * KTOT + kidx[t]], basis[t] * x[src]);
}

__global__ void dense1_kernel(const float* __restrict__ acc1, const float* __restrict__ x,
                              const float* __restrict__ W1, const float* __restrict__ root1,
                              const float* __restrict__ b1, float* __restrict__ h1) {
    __shared__ float w[KTOT * 32];
    for (int l = threadIdx.x; l < KTOT * 32; l += 256) w[l] = W1[l];
    __syncthreads();
    int j = threadIdx.x & 31;
    int nl = threadIdx.x >> 5;
    int n = blockIdx.x * 8 + nl;
    if (n >= NN_NODES) return;
    float s = b1[j] + x[n] * root1[j];
    const float* a = acc1 + n * KTOT;
#pragma unroll
    for (int k = 0; k < KTOT; ++k) s = fmaf(a[k], w[k * 32 + j], s);
    h1[n * 32 + j] = fmaxf(s, 0.0f);
}

// ---------------------------------------------------------------------------
// Per-node LDS accumulation (layers 2/3): acc[48][CIN] in LDS, written out
// coalesced to global accbuf (chunk-local rows).
// ---------------------------------------------------------------------------
template <int CIN>
__global__ __launch_bounds__(256) void accumulate_kernel(
    const int* __restrict__ src_idx, const float* __restrict__ basis,
    const unsigned char* __restrict__ kidx, const int* __restrict__ row_start,
    const int* __restrict__ edge_list, const float* __restrict__ h,
    float* __restrict__ acc, int n0) {
    __shared__ float sacc[KTOT * CIN];
    int n = n0 + blockIdx.x;
    for (int l = threadIdx.x; l < KTOT * CIN; l += 256) sacc[l] = 0.0f;
    __syncthreads();
    int beg = row_start[n];
    int end = row_start[n + 1];
    int i = threadIdx.x % CIN;
    int s0 = threadIdx.x / CIN;
    constexpr int SPAR = 256 / CIN;

    // software-pipelined edge loop: prefetch next (e, src)
    int e = 0, srcn = 0;
    if (beg < end) {
        e = edge_list[beg];
        srcn = src_idx[e];
    }
    for (int idx = beg; idx < end; ++idx) {
        int e_cur = e, src_cur = srcn;
        int nidx = idx + 1;
        if (nidx < end) {
            e = edge_list[nidx];
            srcn = src_idx[e];
        }
        float hv = h[(size_t)src_cur * CIN + i];
#pragma unroll
        for (int s = s0; s < 8; s += SPAR) {
            float b = basis[e_cur * 8 + s];
            int k = kidx[e_cur * 8 + s];
            atomicAdd(&sacc[k * CIN + i], b * hv);
        }
    }
    __syncthreads();
    float* dst = acc + (size_t)blockIdx.x * (KTOT * CIN);
    for (int l = threadIdx.x; l < KTOT * CIN; l += 256) dst[l] = sacc[l];
}

// ---------------------------------------------------------------------------
// Contraction GEMM: out[n0+r, :NN] = relu( A[r,:KK] @ W[KK,NN]
//                                        + Hprev[n0+r,:CP] @ root[CP,NN] + bias )
// Tiles: BM=128, BN=64, BK=16; 256 threads; 8x4 per thread.
// ---------------------------------------------------------------------------
#define GBM 128
#define GBN 64
#define GBK 16

__global__ __launch_bounds__(256) void contract_gemm(
    const float* __restrict__ A, int KK, const float* __restrict__ W, int NN,
    const float* __restrict__ Hprev, int CP, const float* __restrict__ root,
    const float* __restrict__ bias, float* __restrict__ out, int n0, int M) {
    __shared__ float As[GBK][GBM + 4];
    __shared__ float Bs[GBK][GBN];
    int bm = blockIdx.x * GBM;
    int bn = blockIdx.y * GBN;
    int tx = threadIdx.x & 15;
    int ty = threadIdx.x >> 4;
    float acc[8][4];
#pragma unroll
    for (int ii = 0; ii < 8; ++ii)
#pragma unroll
        for (int jj = 0; jj < 4; ++jj) acc[ii][jj] = 0.0f;

    // ---- main K loop over A @ W ----
    for (int k0 = 0; k0 < KK; k0 += GBK) {
#pragma unroll
        for (int it = 0; it < (GBM * GBK) / 256; ++it) {
            int l = threadIdx.x + it * 256;
            int r = l >> 4, kk = l & 15;
            int row = bm + r;
            As[kk][r] = (row < M) ? A[(size_t)row * KK + (k0 + kk)] : 0.0f;
        }
#pragma unroll
        for (int it = 0; it < (GBK * GBN) / 256; ++it) {
            int l = threadIdx.x + it * 256;
            int kk = l >> 6, c = l & 63;
            Bs[kk][c] = W[(size_t)(k0 + kk) * NN + bn + c];
        }
        __syncthreads();
#pragma unroll
        for (int kk = 0; kk < GBK; ++kk) {
            float a[8], b[4];
            *(float4*)&a[0] = *(const float4*)&As[kk][ty * 8];
            *(float4*)&a[4] = *(const float4*)&As[kk][ty * 8 + 4];
            *(float4*)&b[0] = *(const float4*)&Bs[kk][tx * 4];
#pragma unroll
            for (int ii = 0; ii < 8; ++ii)
#pragma unroll
                for (int jj = 0; jj < 4; ++jj) acc[ii][jj] = fmaf(a[ii], b[jj], acc[ii][jj]);
        }
        __syncthreads();
    }

    // ---- root term: Hprev @ root ----
    for (int k0 = 0; k0 < CP; k0 += GBK) {
#pragma unroll
        for (int it = 0; it < (GBM * GBK) / 256; ++it) {
            int l = threadIdx.x + it * 256;
            int r = l >> 4, kk = l & 15;
            int row = bm + r;
            As[kk][r] = (row < M) ? Hprev[(size_t)(n0 + row) * CP + (k0 + kk)] : 0.0f;
        }
#pragma unroll
        for (int it = 0; it < (GBK * GBN) / 256; ++it) {
            int l = threadIdx.x + it * 256;
            int kk = l >> 6, c = l & 63;
            Bs[kk][c] = root[(size_t)(k0 + kk) * NN + bn + c];
        }
        __syncthreads();
#pragma unroll
        for (int kk = 0; kk < GBK; ++kk) {
            float a[8], b[4];
            *(float4*)&a[0] = *(const float4*)&As[kk][ty * 8];
            *(float4*)&a[4] = *(const float4*)&As[kk][ty * 8 + 4];
            *(float4*)&b[0] = *(const float4*)&Bs[kk][tx * 4];
#pragma unroll
            for (int ii = 0; ii < 8; ++ii)
#pragma unroll
                for (int jj = 0; jj < 4; ++jj) acc[ii][jj] = fmaf(a[ii], b[jj], acc[ii][jj]);
        }
        __syncthreads();
    }

    // ---- epilogue: bias + relu + store ----
#pragma unroll
    for (int ii = 0; ii < 8; ++ii) {
        int row = bm + ty * 8 + ii;
        if (row < M) {
#pragma unroll
            for (int jj = 0; jj < 4; ++jj) {
                int col = bn + tx * 4 + jj;
                float v = acc[ii][jj] + bias[col];
                out[(size_t)(n0 + row) * NN + col] = fmaxf(v, 0.0f);
            }
        }
    }
}

// ---------------------------------------------------------------------------
// log_softmax over rows of out[N,128], in place. One wave (64) per row.
// ---------------------------------------------------------------------------
__global__ void logsoftmax_kernel(float* __restrict__ out) {
    int n = blockIdx.x;
    int lane = threadIdx.x;
    float v0 = out[(size_t)n * 128 + lane];
    float v1 = out[(size_t)n * 128 + 64 + lane];
    float m = fmaxf(v0, v1);
#pragma unroll
    for (int off = 32; off > 0; off >>= 1) m = fmaxf(m, __shfl_xor(m, off));
    float s = expf(v0 - m) + expf(v1 - m);
#pragma unroll
    for (int off = 32; off > 0; off >>= 1) s += __shfl_xor(s, off);
    float lse = m + logf(s);
    out[(size_t)n * 128 + lane] = v0 - lse;
    out[(size_t)n * 128 + 64 + lane] = v1 - lse;
}

// ---------------------------------------------------------------------------
// Launch
// ---------------------------------------------------------------------------
extern "C" void kernel_launch(void* const* d_in, const int* in_sizes, int n_in,
                              void* d_out, int out_size, void* d_ws, size_t ws_size,
                              hipStream_t stream) {
    const float* x = (const float*)d_in[0];
    const int* ei = (const int*)d_in[1];
    const float* pseudo = (const float*)d_in[2];
    const float* W1 = (const float*)d_in[3];
    const float* root1 = (const float*)d_in[4];
    const float* b1 = (const float*)d_in[5];
    const float* W2 = (const float*)d_in[6];
    const float* root2 = (const float*)d_in[7];
    const float* b2 = (const float*)d_in[8];
    const float* W3 = (const float*)d_in[9];
    const float* root3 = (const float*)d_in[10];
    const float* b3 = (const float*)d_in[11];
    float* out = (float*)d_out;
    char* ws = (char*)d_ws;

    const int N = NN_NODES, E = NE_EDGES;
    size_t off = 0;
    auto carve = [&](size_t bytes) {
        size_t p = off;
        off += (bytes + 255) & ~(size_t)255;
        return p;
    };
    float* basis = (float*)(ws + carve((size_t)E * 8 * 4));
    unsigned char* kidx = (unsigned char*)(ws + carve((size_t)E * 8));
    int* counts = (int*)(ws + carve((size_t)N * 4 * 2));
    int* cursor = counts + N;
    int* row_start = (int*)(ws + carve((size_t)(N + 1) * 4));
    int* edge_list = (int*)(ws + carve((size_t)E * 4));
    float* h1 = (float*)(ws + carve((size_t)N * 32 * 4));
    float* h2 = (float*)(ws + carve((size_t)N * 64 * 4));
    float* acc1 = (float*)(ws + carve((size_t)N * KTOT * 4));
    size_t rem = (ws_size > off) ? (ws_size - off) : 0;
    float* accbuf = (float*)(ws + off);

    int ch3 = (int)(rem / ((size_t)KTOT * 64 * 4));
    int ch2 = (int)(rem / ((size_t)KTOT * 32 * 4));
    if (ch3 > N) ch3 = N;
    if (ch2 > N) ch2 = N;
    if (ch3 < 1) ch3 = 1;
    if (ch2 < 1) ch2 = 1;

    int egrid = (E + 255) / 256;

    // edge prep
    edge_prep_kernel<<<egrid, 256, 0, stream>>>(pseudo, basis, kidx);

    // CSR
    zero_kernel<<<(2 * N + 255) / 256, 256, 0, stream>>>(counts, 2 * N);
    count_kernel<<<egrid, 256, 0, stream>>>(ei, counts);
    scan_kernel<<<1, 256, 0, stream>>>(counts, row_start);
    fill_kernel<<<egrid, 256, 0, stream>>>(ei, row_start, cursor, edge_list);

    // layer 1
    zero_kernel<<<(N * KTOT + 255) / 256, 256, 0, stream>>>((int*)acc1, N * KTOT);
    scatter1_kernel<<<(E * 8 + 255) / 256, 256, 0, stream>>>(ei, x, basis, kidx, acc1);
    dense1_kernel<<<(N + 7) / 8, 256, 0, stream>>>(acc1, x, W1, root1, b1, h1);

    // layer 2
    for (int n0 = 0; n0 < N; n0 += ch2) {
        int mc = N - n0 < ch2 ? N - n0 : ch2;
        accumulate_kernel<32><<<mc, 256, 0, stream>>>(ei, basis, kidx, row_start, edge_list,
                                                      h1, accbuf, n0);
        dim3 g((mc + GBM - 1) / GBM, 64 / GBN);
        contract_gemm<<<g, 256, 0, stream>>>(accbuf, KTOT * 32, W2, 64, h1, 32, root2, b2,
                                             h2, n0, mc);
    }

    // layer 3 (output logits to d_out)
    for (int n0 = 0; n0 < N; n0 += ch3) {
        int mc = N - n0 < ch3 ? N - n0 : ch3;
        accumulate_kernel<64><<<mc, 256, 0, stream>>>(ei, basis, kidx, row_start, edge_list,
                                                      h2, accbuf, n0);
        dim3 g((mc + GBM - 1) / GBM, 128 / GBN);
        contract_gemm<<<g, 256, 0, stream>>>(accbuf, KTOT * 64, W3, 128, h2, 64, root3, b3,
                                             out, n0, mc);
    }

    // log_softmax in place on d_out
    logsoftmax_kernel<<<N, 64, 0, stream>>>(out);
}